// Round 10
// baseline (395.159 us; speedup 1.0000x reference)
//
#include <hip/hip_runtime.h>
#include <hip/hip_bf16.h>
#include <stdint.h>

typedef unsigned short u16;
typedef __bf16 bf16x8 __attribute__((ext_vector_type(8)));
typedef u16 u16x8 __attribute__((ext_vector_type(8)));
typedef float f32x4 __attribute__((ext_vector_type(4)));

#define SEQ   1024
#define DM    1024
#define NHEADS 16
#define HDIM  64
#define VOC   32000
#define FFD   2816
#define NLAY  2

__device__ __forceinline__ u16 f2b(float f) {
    unsigned x = __builtin_bit_cast(unsigned, f);
    unsigned r = x + 0x7fffu + ((x >> 16) & 1u);
    return (u16)(r >> 16);
}
__device__ __forceinline__ float b2f(u16 u) {
    unsigned x = ((unsigned)u) << 16;
    return __builtin_bit_cast(float, x);
}
__device__ __forceinline__ float grpmax16(float v) {
    v = fmaxf(v, __shfl_xor(v, 1)); v = fmaxf(v, __shfl_xor(v, 2));
    v = fmaxf(v, __shfl_xor(v, 4)); v = fmaxf(v, __shfl_xor(v, 8));
    return v;
}
__device__ __forceinline__ float grpsum16(float v) {
    v += __shfl_xor(v, 1); v += __shfl_xor(v, 2);
    v += __shfl_xor(v, 4); v += __shfl_xor(v, 8);
    return v;
}

// async global->LDS, 16 bytes per lane. LDS dest must be wave-uniform base + lane*16.
__device__ __forceinline__ void gll16(const void* g, void* l) {
    __builtin_amdgcn_global_load_lds(
        (__attribute__((address_space(1))) void*)(uintptr_t)g,
        (__attribute__((address_space(3))) void*)(uint32_t)(uintptr_t)l,
        16, 0, 0);
}
template <int N> __device__ __forceinline__ void vwait() {
    if constexpr (N == 0)       asm volatile("s_waitcnt vmcnt(0)" ::: "memory");
    else if constexpr (N == 4)  asm volatile("s_waitcnt vmcnt(4)" ::: "memory");
    else if constexpr (N == 8)  asm volatile("s_waitcnt vmcnt(8)" ::: "memory");
    else if constexpr (N == 10) asm volatile("s_waitcnt vmcnt(10)" ::: "memory");
    else if constexpr (N == 16) asm volatile("s_waitcnt vmcnt(16)" ::: "memory");
}
// bijective XCD swizzle for any nwg (m204): per-XCD contiguous logical chunks.
__device__ __forceinline__ int xcd_swz(int bid, int nwg) {
    const int q = nwg >> 3, r = nwg & 7;
    const int xcd = bid & 7, j = bid >> 3;
    const int start = (xcd < r) ? xcd * (q + 1) : r * (q + 1) + (xcd - r) * q;
    return start + j;
}

// ---------------- fp32 -> bf16 weight conversion: lane-contiguous granules ----------------
// granule = float4 (4 elems). Lane i handles flat granule base+i -> 16B/lane coalesced
// loads, contiguous 8B/lane stores. 4-deep batch for ILP.
struct CvtArgs { const float* s[8]; u16* d[8]; int cum[9]; };
__global__ __launch_bounds__(256) void cvt_all_kernel(CvtArgs a) {
    const int nt = gridDim.x * 256;
    const int total = a.cum[8];
    int u = blockIdx.x * 256 + threadIdx.x;
    for (; u + 3 * nt < total; u += 4 * nt) {
        float4 x[4]; int gi[4], li[4];
#pragma unroll
        for (int b = 0; b < 4; ++b) {
            const int uu = u + b * nt;
            int g = 0;
#pragma unroll
            for (int k = 1; k < 8; ++k) g += (uu >= a.cum[k]) ? 1 : 0;
            gi[b] = g;
            li[b] = uu - a.cum[g];
            x[b] = ((const float4*)a.s[g])[li[b]];
        }
#pragma unroll
        for (int b = 0; b < 4; ++b) {
            ushort4 p;
            p.x = f2b(x[b].x); p.y = f2b(x[b].y); p.z = f2b(x[b].z); p.w = f2b(x[b].w);
            ((ushort4*)a.d[gi[b]])[li[b]] = p;
        }
    }
    for (; u < total; u += nt) {
        int g = 0;
#pragma unroll
        for (int k = 1; k < 8; ++k) g += (u >= a.cum[k]) ? 1 : 0;
        const int local = u - a.cum[g];
        const float4 x = ((const float4*)a.s[g])[local];
        ushort4 p;
        p.x = f2b(x.x); p.y = f2b(x.y); p.z = f2b(x.z); p.w = f2b(x.w);
        ((ushort4*)a.d[g])[local] = p;
    }
}

// ---------------- embedding gather ----------------
__global__ __launch_bounds__(256) void embed_kernel(const int* __restrict__ tok,
    const float* __restrict__ emb, float* __restrict__ h) {
    const int l = blockIdx.x;
    const int t = tok[l];
    ((float4*)(h + (size_t)l * DM))[threadIdx.x] =
        ((const float4*)(emb + (size_t)t * DM))[threadIdx.x];
}

// ---------------- rope tables ----------------
__global__ __launch_bounds__(256) void ropetab_kernel(float* __restrict__ cosb,
                                                      float* __restrict__ sinb) {
    const int idx = blockIdx.x * 256 + threadIdx.x;   // < SEQ*32
    const int l = idx >> 5, j = idx & 31;
    const float inv = __expf(-((float)j * (1.0f / 32.0f)) * 13.122363377404328f); // ln(500000)
    const float ang = (float)l * inv;
    cosb[idx] = cosf(ang);
    sinb[idx] = sinf(ang);
}

// ---------------- transfusion span ids + per-64-token-tile span bitmask ----------------
__global__ void span_kernel(const int* __restrict__ tok, int* __restrict__ span,
                            int* __restrict__ tmask) {
    __shared__ int sb[SEQ], se[SEQ];
    __shared__ int tm[SEQ / 64];
    const int t = threadIdx.x;
    const int v = tok[t];
    const int bo = (v == 31998) ? 1 : 0;
    const int eo = (v == 31999) ? 1 : 0;
    sb[t] = bo; se[t] = eo;
    if (t < SEQ / 64) tm[t] = 0;
    __syncthreads();
    for (int o = 1; o < SEQ; o <<= 1) {
        int a = 0, b = 0;
        if (t >= o) { a = sb[t - o]; b = se[t - o]; }
        __syncthreads();
        sb[t] += a; se[t] += b;
        __syncthreads();
    }
    const int bc = sb[t];
    const int ec = se[t] - eo;           // exclusive eoi cumsum
    const int id = (bc > ec) ? bc : 0;
    span[t] = id;
    if (id > 0) atomicOr(&tm[t >> 6], 1 << ((id - 1) & 31));
    __syncthreads();
    if (t < SEQ / 64) tmask[t] = tm[t];
}

// ---------------- rmsnorm (fp32 in -> bf16 out) ----------------
__global__ __launch_bounds__(256) void rmsnorm_kernel(const float* __restrict__ x,
    const float* __restrict__ w, u16* __restrict__ o) {
    const int row = blockIdx.x;
    const float4 xv = ((const float4*)(x + (size_t)row * DM))[threadIdx.x];
    float ss = xv.x * xv.x + xv.y * xv.y + xv.z * xv.z + xv.w * xv.w;
    for (int off = 32; off; off >>= 1) ss += __shfl_xor(ss, off);
    __shared__ float red[4];
    const int lane = threadIdx.x & 63, wvi = threadIdx.x >> 6;
    if (lane == 0) red[wvi] = ss;
    __syncthreads();
    const float tot = red[0] + red[1] + red[2] + red[3];
    const float sc = rsqrtf(tot * (1.0f / (float)DM) + 1e-5f);
    const float4 wv4 = ((const float4*)w)[threadIdx.x];
    ushort4 ov;
    ov.x = f2b(xv.x * sc * wv4.x);
    ov.y = f2b(xv.y * sc * wv4.y);
    ov.z = f2b(xv.z * sc * wv4.z);
    ov.w = f2b(xv.w * sc * wv4.w);
    ((ushort4*)(o + (size_t)row * DM))[threadIdx.x] = ov;
}

// ======================= pipelined GEMM (BK=64, counted vmcnt) =======================
// LDS rows 128B; granule swizzle gr' = gr ^ (row&7) conflict-free; swizzle baked into
// per-thread staging pointers. Per K-tile: stage t+1 -> p^1 ; vwait<LOADS> ; s_barrier ;
// ds_read p + MFMA ; s_barrier. No vmcnt(0) drain in the main loop.

// ---------------- generic pipelined GEMM, fp32 out (+optional residual) ----------------
template <int RESID, int BM, int BN>
__global__ __launch_bounds__(256) void gemm_p_kernel(const u16* __restrict__ A,
    const u16* __restrict__ B, float* __restrict__ C, const float* __restrict__ res,
    int N, int K) {
    constexpr int AL = BM / 32, BL = BN / 32, LOADS = AL + BL;
    constexpr int MF = BM / 32, NF = BN / 32;
    __shared__ __align__(16) u16 sA[2][BM * 64];
    __shared__ __align__(16) u16 sB[2][BN * 64];
    const int nwg = gridDim.x * gridDim.y;
    const int lid = xcd_swz(blockIdx.y * gridDim.x + blockIdx.x, nwg);
    const int tm = (lid % gridDim.x) * BM, tn = (lid / gridDim.x) * BN;
    const int tid = threadIdx.x, lane = tid & 63, wid = tid >> 6;
    const int wm = wid >> 1, wn = wid & 1, fr = lane & 15, g = lane >> 4;

    const u16* ap[AL]; const u16* bp[BL];
#pragma unroll
    for (int j = 0; j < AL; ++j) {
        const int idx = j * 256 + tid, r = idx >> 3, gr = (idx & 7) ^ (r & 7);
        ap[j] = A + (size_t)(tm + r) * K + gr * 8;
    }
#pragma unroll
    for (int j = 0; j < BL; ++j) {
        const int idx = j * 256 + tid, r = idx >> 3, gr = (idx & 7) ^ (r & 7);
        bp[j] = B + (size_t)(tn + r) * K + gr * 8;
    }

    f32x4 acc[MF][NF] = {};
    const int NT = K >> 6;
#pragma unroll
    for (int j = 0; j < AL; ++j) gll16(ap[j], &sA[0][(j * 256 + tid) * 8]);
#pragma unroll
    for (int j = 0; j < BL; ++j) gll16(bp[j], &sB[0][(j * 256 + tid) * 8]);

    int p = 0;
    for (int t = 0; t < NT; ++t) {
        if (t + 1 < NT) {
#pragma unroll
            for (int j = 0; j < AL; ++j) gll16(ap[j] + (t + 1) * 64, &sA[p ^ 1][(j * 256 + tid) * 8]);
#pragma unroll
            for (int j = 0; j < BL; ++j) gll16(bp[j] + (t + 1) * 64, &sB[p ^ 1][(j * 256 + tid) * 8]);
            vwait<LOADS>();
        } else {
            vwait<0>();
        }
        __builtin_amdgcn_s_barrier();          // all waves' tile-t data resident
        __builtin_amdgcn_sched_barrier(0);
        bf16x8 af[MF][2], bfv[NF][2];
#pragma unroll
        for (int m = 0; m < MF; ++m)
#pragma unroll
            for (int ks = 0; ks < 2; ++ks) {
                const int row = wm * (BM / 2) + m * 16 + fr;
                const int gr = (ks * 4 + g) ^ (row & 7);
                af[m][ks] = *(const bf16x8*)&sA[p][row * 64 + gr * 8];
            }
#pragma unroll
        for (int n = 0; n < NF; ++n)
#pragma unroll
            for (int ks = 0; ks < 2; ++ks) {
                const int row = wn * (BN / 2) + n * 16 + fr;
                const int gr = (ks * 4 + g) ^ (row & 7);
                bfv[n][ks] = *(const bf16x8*)&sB[p][row * 64 + gr * 8];
            }
        __builtin_amdgcn_s_setprio(1);
#pragma unroll
        for (int m = 0; m < MF; ++m)
#pragma unroll
            for (int n = 0; n < NF; ++n)
#pragma unroll
                for (int ks = 0; ks < 2; ++ks)
                    acc[m][n] = __builtin_amdgcn_mfma_f32_16x16x32_bf16(af[m][ks], bfv[n][ks], acc[m][n], 0, 0, 0);
        __builtin_amdgcn_s_setprio(0);
        __builtin_amdgcn_s_barrier();          // reads of buf p closed before next writes
        p ^= 1;
    }

    const int cr = (lane >> 4) * 4, cc = lane & 15;
#pragma unroll
    for (int m = 0; m < MF; ++m)
#pragma unroll
        for (int n = 0; n < NF; ++n) {
            const int row0 = tm + wm * (BM / 2) + m * 16 + cr;
            const int col = tn + wn * (BN / 2) + n * 16 + cc;
#pragma unroll
            for (int r = 0; r < 4; ++r) {
                const size_t idx = (size_t)(row0 + r) * N + col;
                float v = acc[m][n][r];
                if (RESID) v += res[idx];
                C[idx] = v;
            }
        }
}

// ======================= 256x256 / BK=64 / 8-wave phase-interleaved GEMM =======================
// m201-style: per K-tile 4 quadrant phases {ds_read frags ; setprio MFMA ; s_barrier}.
template <int RESID>
__global__ __launch_bounds__(512, 2) void gemm_big_kernel(const u16* __restrict__ A,
    const u16* __restrict__ B, float* __restrict__ C, const float* __restrict__ res,
    int N, int K) {
    __shared__ __align__(16) u16 sA[2][256 * 64];
    __shared__ __align__(16) u16 sB[2][256 * 64];
    const int nwg = gridDim.x * gridDim.y;
    const int lid = xcd_swz(blockIdx.y * gridDim.x + blockIdx.x, nwg);
    const int tm = (lid % gridDim.x) * 256;
    const int tn = (lid / gridDim.x) * 256;
    const int tid = threadIdx.x, lane = tid & 63, wid = tid >> 6;
    const int wm = wid >> 2, wn = wid & 3;       // 2 x 4 waves, per-wave 128x64
    const int fr = lane & 15, g = lane >> 4;

    const u16* ap[4]; const u16* bp[4];
#pragma unroll
    for (int j = 0; j < 4; ++j) {
        const int idx = j * 512 + tid, r = idx >> 3, gr = (idx & 7) ^ (r & 7);
        ap[j] = A + (size_t)(tm + r) * K + gr * 8;
        bp[j] = B + (size_t)(tn + r) * K + gr * 8;
    }

    f32x4 acc[8][4] = {};
    const int NT = K >> 6;
#pragma unroll
    for (int j = 0; j < 4; ++j) gll16(ap[j], &sA[0][(j * 512 + tid) * 8]);
#pragma unroll
    for (int j = 0; j < 4; ++j) gll16(bp[j], &sB[0][(j * 512 + tid) * 8]);

    int p = 0;
    for (int t = 0; t < NT; ++t) {
        if (t + 1 < NT) {
#pragma unroll
            for (int j = 0; j < 4; ++j) gll16(ap[j] + (t + 1) * 64, &sA[p ^ 1][(j * 512 + tid) * 8]);
#pragma unroll
            for (int j = 0; j < 4; ++j) gll16(bp[j] + (t + 1) * 64, &sB[p ^ 1][(j * 512 + tid) * 8]);
            vwait<8>();
        } else {
            vwait<0>();
        }
        __builtin_amdgcn_s_barrier();            // tile-t resident for all waves
        __builtin_amdgcn_sched_barrier(0);
        bf16x8 bfv[4][2];
#pragma unroll
        for (int mq = 0; mq < 4; ++mq) {         // 4 phases per K-tile
            if (mq == 0) {
#pragma unroll
                for (int n = 0; n < 4; ++n)
#pragma unroll
                    for (int ks = 0; ks < 2; ++ks) {
                        const int row = wn * 64 + n * 16 + fr;
                        const int gr = (ks * 4 + g) ^ (row & 7);
                        bfv[n][ks] = *(const bf16x8*)&sB[p][row * 64 + gr * 8];
                    }
            }
            bf16x8 af[2][2];
#pragma unroll
            for (int i = 0; i < 2; ++i)
#pragma unroll
                for (int ks = 0; ks < 2; ++ks) {
                    const int row = wm * 128 + (mq * 2 + i) * 16 + fr;
                    const int gr = (ks * 4 + g) ^ (row & 7);
                    af[i][ks] = *(const bf16x8*)&sA[p][row * 64 + gr * 8];
                }
            __builtin_amdgcn_s_setprio(1);
#pragma unroll
            for (int i = 0; i < 2; ++i)
#pragma unroll
                for (int n = 0; n < 4; ++n)
#pragma unroll
                    for (int ks = 0; ks < 2; ++ks)
                        acc[mq * 2 + i][n] = __builtin_amdgcn_mfma_f32_16x16x32_bf16(
                            af[i][ks], bfv[n][ks], acc[mq * 2 + i][n], 0, 0, 0);
            __builtin_amdgcn_s_setprio(0);
            __builtin_amdgcn_s_barrier();        // phase boundary (last one closes WAR)
        }
        p ^= 1;
    }

    const int cr = (lane >> 4) * 4, cc = lane & 15;
#pragma unroll
    for (int m = 0; m < 8; ++m)
#pragma unroll
        for (int n = 0; n < 4; ++n) {
            const int row0 = tm + wm * 128 + m * 16 + cr;
            const int col = tn + wn * 64 + n * 16 + cc;
#pragma unroll
            for (int r = 0; r < 4; ++r) {
                const size_t idx = (size_t)(row0 + r) * N + col;
                float v = acc[m][n][r];
                if (RESID) v += res[idx];
                C[idx] = v;
            }
        }
}

// ---------------- fused QKV GEMM (128x128) + RoPE + bf16 cast ----------------
__global__ __launch_bounds__(256) void qkv_kernel(const u16* __restrict__ A,
    const u16* __restrict__ Bq, const u16* __restrict__ Bk, const u16* __restrict__ Bv,
    const float* __restrict__ cosb, const float* __restrict__ sinb,
    u16* __restrict__ qb, u16* __restrict__ kb, u16* __restrict__ vb) {
    __shared__ __align__(16) u16 sA[2][128 * 64];
    __shared__ __align__(16) u16 sB[2][128 * 64];
    const int lid = xcd_swz(blockIdx.y * gridDim.x + blockIdx.x, 8 * 24);
    const int tm = (lid % 8) * 128;
    const int yy = lid / 8;
    const int mat = yy >> 3;
    const int tn = (yy & 7) * 128;
    const u16* B = (mat == 0) ? Bq : (mat == 1) ? Bk : Bv;
    u16* out = (mat == 0) ? qb : (mat == 1) ? kb : vb;
    const int tid = threadIdx.x, lane = tid & 63, wid = tid >> 6;
    const int wm = wid >> 1, wn = wid & 1, fr = lane & 15, g = lane >> 4;

    const u16* ap[4]; const u16* bp[4];
#pragma unroll
    for (int j = 0; j < 4; ++j) {
        const int idx = j * 256 + tid, r = idx >> 3, gr = (idx & 7) ^ (r & 7);
        ap[j] = A + (size_t)(tm + r) * DM + gr * 8;
        bp[j] = B + (size_t)(tn + r) * DM + gr * 8;
    }

    f32x4 acc[4][4] = {};
#pragma unroll
    for (int j = 0; j < 4; ++j) gll16(ap[j], &sA[0][(j * 256 + tid) * 8]);
#pragma unroll
    for (int j = 0; j < 4; ++j) gll16(bp[j], &sB[0][(j * 256 + tid) * 8]);

    int p = 0;
    for (int t = 0; t < DM / 64; ++t) {
        if (t + 1 < DM / 64) {
#pragma unroll
            for (int j = 0; j < 4; ++j) gll16(ap[j] + (t + 1) * 64, &sA[p ^ 1][(j * 256 + tid) * 8]);
#pragma unroll
            for (int j = 0; j < 4; ++j) gll16(bp[j] + (t + 1) * 64, &sB[p ^ 1][(j * 256 + tid) * 8]);
            vwait<8>();
        } else {
            vwait<0>();
        }
        __builtin_amdgcn_s_barrier();
        __builtin_amdgcn_sched_barrier(0);
        bf16x8 af[4][2], bfv[4][2];
#pragma unroll
        for (int m = 0; m < 4; ++m)
#pragma unroll
            for (int ks = 0; ks < 2; ++ks) {
                const int row = wm * 64 + m * 16 + fr;
                const int gr = (ks * 4 + g) ^ (row & 7);
                af[m][ks] = *(const bf16x8*)&sA[p][row * 64 + gr * 8];
            }
#pragma unroll
        for (int n = 0; n < 4; ++n)
#pragma unroll
            for (int ks = 0; ks < 2; ++ks) {
                const int row = wn * 64 + n * 16 + fr;
                const int gr = (ks * 4 + g) ^ (row & 7);
                bfv[n][ks] = *(const bf16x8*)&sB[p][row * 64 + gr * 8];
            }
        __builtin_amdgcn_s_setprio(1);
#pragma unroll
        for (int m = 0; m < 4; ++m)
#pragma unroll
            for (int n = 0; n < 4; ++n)
#pragma unroll
                for (int ks = 0; ks < 2; ++ks)
                    acc[m][n] = __builtin_amdgcn_mfma_f32_16x16x32_bf16(af[m][ks], bfv[n][ks], acc[m][n], 0, 0, 0);
        __builtin_amdgcn_s_setprio(0);
        __builtin_amdgcn_s_barrier();
        p ^= 1;
    }

    const int cr = (lane >> 4) * 4, cc = lane & 15;
    if (mat < 2) {
#pragma unroll
        for (int m = 0; m < 4; ++m)
#pragma unroll
            for (int n = 0; n < 4; ++n) {
                const int row0 = tm + wm * 64 + m * 16 + cr;
                const int col = tn + wn * 64 + n * 16 + cc;
                const int j = (n * 16 + cc) >> 1;    // rope pair index within head
#pragma unroll
                for (int r = 0; r < 4; ++r) {
                    const int row = row0 + r;
                    const float c = cosb[row * 32 + j];
                    const float s = sinb[row * 32 + j];
                    const float v = acc[m][n][r];
                    const float pv = __shfl_xor(v, 1);
                    const float o = (cc & 1) ? (pv * s + v * c) : (v * c - pv * s);
                    out[(size_t)row * DM + col] = f2b(o);
                }
            }
    } else {
#pragma unroll
        for (int m = 0; m < 4; ++m)
#pragma unroll
            for (int n = 0; n < 4; ++n) {
                const int row0 = tm + wm * 64 + m * 16 + cr;
                const int col = tn + wn * 64 + n * 16 + cc;
#pragma unroll
                for (int r = 0; r < 4; ++r)
                    out[(size_t)(row0 + r) * DM + col] = f2b(acc[m][n][r]);
            }
    }
}

// ---------------- fused w1/w3 GEMM (64x128 dual-B) + SiLU*mul -> bf16 ----------------
__global__ __launch_bounds__(256) void ffn13_kernel(const u16* __restrict__ A,
    const u16* __restrict__ B1, const u16* __restrict__ B3, u16* __restrict__ Z) {
    __shared__ __align__(16) u16 sA[2][64 * 64];
    __shared__ __align__(16) u16 sB1[2][128 * 64];
    __shared__ __align__(16) u16 sB3[2][128 * 64];
    const int lid = xcd_swz(blockIdx.y * gridDim.x + blockIdx.x, 16 * 22);
    const int tm = (lid % 16) * 64;
    const int tn = (lid / 16) * 128;
    const int tid = threadIdx.x, lane = tid & 63, wid = tid >> 6;
    const int wm = wid >> 1, wn = wid & 1, fr = lane & 15, g = lane >> 4;

    const u16* ap[2]; const u16* b1p[4]; const u16* b3p[4];
#pragma unroll
    for (int j = 0; j < 2; ++j) {
        const int idx = j * 256 + tid, r = idx >> 3, gr = (idx & 7) ^ (r & 7);
        ap[j] = A + (size_t)(tm + r) * DM + gr * 8;
    }
#pragma unroll
    for (int j = 0; j < 4; ++j) {
        const int idx = j * 256 + tid, r = idx >> 3, gr = (idx & 7) ^ (r & 7);
        b1p[j] = B1 + (size_t)(tn + r) * DM + gr * 8;
        b3p[j] = B3 + (size_t)(tn + r) * DM + gr * 8;
    }

    f32x4 acc1[2][4] = {}, acc3[2][4] = {};
#pragma unroll
    for (int j = 0; j < 2; ++j) gll16(ap[j], &sA[0][(j * 256 + tid) * 8]);
#pragma unroll
    for (int j = 0; j < 4; ++j) gll16(b1p[j], &sB1[0][(j * 256 + tid) * 8]);
#pragma unroll
    for (int j = 0; j < 4; ++j) gll16(b3p[j], &sB3[0][(j * 256 + tid) * 8]);

    int p = 0;
    for (int t = 0; t < DM / 64; ++t) {
        if (t + 1 < DM / 64) {
#pragma unroll
            for (int j = 0; j < 2; ++j) gll16(ap[j] + (t + 1) * 64, &sA[p ^ 1][(j * 256 + tid) * 8]);
#pragma unroll
            for (int j = 0; j < 4; ++j) gll16(b1p[j] + (t + 1) * 64, &sB1[p ^ 1][(j * 256 + tid) * 8]);
#pragma unroll
            for (int j = 0; j < 4; ++j) gll16(b3p[j] + (t + 1) * 64, &sB3[p ^ 1][(j * 256 + tid) * 8]);
            vwait<10>();
        } else {
            vwait<0>();
        }
        __builtin_amdgcn_s_barrier();
        __builtin_amdgcn_sched_barrier(0);
        bf16x8 af[2][2], b1v[4][2], b3v[4][2];
#pragma unroll
        for (int m = 0; m < 2; ++m)
#pragma unroll
            for (int ks = 0; ks < 2; ++ks) {
                const int row = wm * 32 + m * 16 + fr;
                const int gr = (ks * 4 + g) ^ (row & 7);
                af[m][ks] = *(const bf16x8*)&sA[p][row * 64 + gr * 8];
            }
#pragma unroll
        for (int n = 0; n < 4; ++n)
#pragma unroll
            for (int ks = 0; ks < 2; ++ks) {
                const int row = wn * 64 + n * 16 + fr;
                const int gr = (ks * 4 + g) ^ (row & 7);
                b1v[n][ks] = *(const bf16x8*)&sB1[p][row * 64 + gr * 8];
                b3v[n][ks] = *(const bf16x8*)&sB3[p][row * 64 + gr * 8];
            }
        __builtin_amdgcn_s_setprio(1);
#pragma unroll
        for (int m = 0; m < 2; ++m)
#pragma unroll
            for (int n = 0; n < 4; ++n)
#pragma unroll
                for (int ks = 0; ks < 2; ++ks) {
                    acc1[m][n] = __builtin_amdgcn_mfma_f32_16x16x32_bf16(af[m][ks], b1v[n][ks], acc1[m][n], 0, 0, 0);
                    acc3[m][n] = __builtin_amdgcn_mfma_f32_16x16x32_bf16(af[m][ks], b3v[n][ks], acc3[m][n], 0, 0, 0);
                }
        __builtin_amdgcn_s_setprio(0);
        __builtin_amdgcn_s_barrier();
        p ^= 1;
    }

    const int cr = (lane >> 4) * 4, cc = lane & 15;
#pragma unroll
    for (int m = 0; m < 2; ++m)
#pragma unroll
        for (int n = 0; n < 4; ++n) {
            const int row0 = tm + wm * 32 + m * 16 + cr;
            const int col = tn + wn * 64 + n * 16 + cc;
#pragma unroll
            for (int r = 0; r < 4; ++r) {
                const float a1 = acc1[m][n][r];
                const float a3 = acc3[m][n][r];
                const float z = a1 / (1.f + __expf(-a1)) * a3;
                Z[(size_t)(row0 + r) * FFD + col] = f2b(z);
            }
        }
}

// ---------------- flash attention: block = (64 q-rows, 1 head), 4 waves ----------------
// KV-tile skip: tiles beyond the causal frontier processed only if span bitmasks overlap.
__global__ __launch_bounds__(256) void fattn_kernel(const u16* __restrict__ qb,
    const u16* __restrict__ kb, const u16* __restrict__ vb,
    const int* __restrict__ span, const int* __restrict__ tmask, u16* __restrict__ ob) {
    __shared__ __align__(16) u16 sK[64][72];   // K rows, padded
    __shared__ __align__(16) u16 sVT[64][72];  // V transposed: [d][key]
    __shared__ __align__(16) u16 sP[4][16][72];// per-wave P tile
    const int tid = threadIdx.x, lane = tid & 63, wq = tid >> 6;
    const int g = lane >> 4, fr = lane & 15;
    const int head = blockIdx.y;
    const int qbase = blockIdx.x * 64;
    const int qmask = tmask[blockIdx.x];

    bf16x8 qfr[2];
    {
        const u16* qp = qb + (size_t)(qbase + wq * 16 + fr) * DM + head * HDIM + g * 8;
        qfr[0] = *(const bf16x8*)(qp);
        qfr[1] = *(const bf16x8*)(qp + 32);
    }
    int sq[4];
#pragma unroll
    for (int r = 0; r < 4; ++r) sq[r] = span[qbase + wq * 16 + g * 4 + r];

    float m_old[4] = {-1e30f, -1e30f, -1e30f, -1e30f};
    float lsum[4] = {0.f, 0.f, 0.f, 0.f};
    f32x4 acc[4] = {};

    for (int kt = 0; kt < SEQ / 64; ++kt) {
        const int kb0 = kt * 64;
        if (kb0 > qbase && (qmask & tmask[kt]) == 0) continue;   // block-uniform skip
        __syncthreads();
        {
            const int r = tid >> 2, c0 = (tid & 3) * 16;
            const u16* src = kb + (size_t)(kb0 + r) * DM + head * HDIM + c0;
            *(u16x8*)&sK[r][c0]     = *(const u16x8*)(src);
            *(u16x8*)&sK[r][c0 + 8] = *(const u16x8*)(src + 8);
        }
        {
            const int k = tid & 63, d0 = (tid >> 6) * 16;
            const u16* src = vb + (size_t)(kb0 + k) * DM + head * HDIM + d0;
            const u16x8 v0 = *(const u16x8*)(src);
            const u16x8 v1 = *(const u16x8*)(src + 8);
#pragma unroll
            for (int j = 0; j < 8; ++j) {
                sVT[d0 + j][k]     = v0[j];
                sVT[d0 + 8 + j][k] = v1[j];
            }
        }
        __syncthreads();

        f32x4 accs[4] = {};
        __builtin_amdgcn_s_setprio(1);
#pragma unroll
        for (int nf = 0; nf < 4; ++nf)
#pragma unroll
            for (int kf = 0; kf < 2; ++kf) {
                const bf16x8 kfv = *(const bf16x8*)&sK[nf * 16 + fr][g * 8 + kf * 32];
                accs[nf] = __builtin_amdgcn_mfma_f32_16x16x32_bf16(qfr[kf], kfv, accs[nf], 0, 0, 0);
            }
        __builtin_amdgcn_s_setprio(0);

        float sv[4][4]; bool al[4][4];
        if (kb0 + 63 <= qbase) {             // fully-causal tile: all allowed
#pragma unroll
            for (int nf = 0; nf < 4; ++nf)
#pragma unroll
                for (int r = 0; r < 4; ++r) {
                    al[nf][r] = true;
                    sv[nf][r] = accs[nf][r] * 0.125f;
                }
        } else {
            int spk[4];
#pragma unroll
            for (int nf = 0; nf < 4; ++nf) spk[nf] = span[kb0 + nf * 16 + fr];
#pragma unroll
            for (int nf = 0; nf < 4; ++nf) {
                const int key = kb0 + nf * 16 + fr;
#pragma unroll
                for (int r = 0; r < 4; ++r) {
                    const int q = qbase + wq * 16 + g * 4 + r;
                    al[nf][r] = (key <= q) || (sq[r] > 0 && spk[nf] == sq[r]);
                    sv[nf][r] = al[nf][r] ? accs[nf][r] * 0.125f : -1e30f;
                }
            }
        }
        float alpha[4], ls[4];
#pragma unroll
        for (int r = 0; r < 4; ++r) {
            float mn = fmaxf(fmaxf(sv[0][r], sv[1][r]), fmaxf(sv[2][r], sv[3][r]));
            mn = grpmax16(mn);
            const float mnew = fmaxf(m_old[r], mn);
            alpha[r] = __expf(m_old[r] - mnew);
            m_old[r] = mnew;
            ls[r] = 0.f;
        }
        u16 pb[4][4];
#pragma unroll
        for (int nf = 0; nf < 4; ++nf)
#pragma unroll
            for (int r = 0; r < 4; ++r) {
                const float p = al[nf][r] ? __expf(sv[nf][r] - m_old[r]) : 0.f;
                ls[r] += p;
                pb[nf][r] = f2b(p);
            }
#pragma unroll
        for (int r = 0; r < 4; ++r) {
            lsum[r] = lsum[r] * alpha[r] + grpsum16(ls[r]);
#pragma unroll
            for (int nf = 0; nf < 4; ++nf) acc[nf][r] *= alpha[r];
        }
#pragma unroll
        for (int nf = 0; nf < 4; ++nf)
#pragma unroll
            for (int r = 0; r < 4; ++r)
                sP[wq][g * 4 + r][nf * 16 + fr] = pb[nf][r];

        __builtin_amdgcn_s_setprio(1);
#pragma unroll
        for (int nf = 0; nf < 4; ++nf)
#pragma unroll
            for (int kf = 0; kf < 2; ++kf) {
                const bf16x8 pa  = *(const bf16x8*)&sP[wq][fr][g * 8 + kf * 32];
                const bf16x8 vtb = *(const bf16x8*)&sVT[nf * 16 + fr][g * 8 + kf * 32];
                acc[nf] = __builtin_amdgcn_mfma_f32_16x16x32_bf16(pa, vtb, acc[nf], 0, 0, 0);
            }
        __builtin_amdgcn_s_setprio(0);
    }

#pragma unroll
    for (int nf = 0; nf < 4; ++nf)
#pragma unroll
        for (int r = 0; r < 4; ++r) {
            const int q = qbase + wq * 16 + g * 4 + r;
            const int d = nf * 16 + fr;
            ob[(size_t)q * DM + head * HDIM + d] = f2b(acc[nf][r] / lsum[r]);
        }
}

extern "C" void kernel_launch(void* const* d_in, const int* in_sizes, int n_in,
                              void* d_out, int out_size, void* d_ws, size_t ws_size,
                              hipStream_t stream) {
    (void)in_sizes; (void)n_in; (void)out_size; (void)ws_size;
    const int*   tokens   = (const int*)d_in[0];
    const float* tok_emb  = (const float*)d_in[1];
    const float* wq       = (const float*)d_in[2];
    const float* wk       = (const float*)d_in[3];
    const float* wvw      = (const float*)d_in[4];
    const float* wo       = (const float*)d_in[5];
    const float* w1       = (const float*)d_in[6];
    const float* w2       = (const float*)d_in[7];
    const float* w3       = (const float*)d_in[8];
    const float* attn_nw  = (const float*)d_in[9];
    const float* ffn_nw   = (const float*)d_in[10];
    const float* final_nw = (const float*)d_in[11];
    const float* w_out    = (const float*)d_in[12];
    float* logits = (float*)d_out;

    char* ws = (char*)d_ws;
    size_t off = 0;
    auto alloc = [&](size_t b) { size_t o = off; off += (b + 255) & ~(size_t)255; return o; };
    float* h    = (float*)(ws + alloc((size_t)SEQ * DM * 4));
    u16*   xn   = (u16*)  (ws + alloc((size_t)SEQ * DM * 2));
    u16*   qb   = (u16*)  (ws + alloc((size_t)SEQ * DM * 2));
    u16*   kb   = (u16*)  (ws + alloc((size_t)SEQ * DM * 2));
    u16*   vb   = (u16*)  (ws + alloc((size_t)SEQ * DM * 2));
    u16*   ab   = (u16*)  (ws + alloc((size_t)SEQ * DM * 2));
    u16*   zb   = (u16*)  (ws + alloc((size_t)SEQ * FFD * 2));
    float* cosb = (float*)(ws + alloc((size_t)SEQ * 32 * 4));
    float* sinb = (float*)(ws + alloc((size_t)SEQ * 32 * 4));
    int*   span = (int*)  (ws + alloc((size_t)SEQ * 4));
    int*   tmask= (int*)  (ws + alloc((size_t)(SEQ / 64) * 4));
    // bf16 weight copies
    const size_t nQ = (size_t)NLAY * DM * DM;     // wq/wk/wv/wo each
    const size_t nF = (size_t)NLAY * FFD * DM;    // w1/w2/w3 each
    const size_t nO = (size_t)VOC * DM;           // w_out
    u16* wqb = (u16*)(ws + alloc(nQ * 2));
    u16* wkb = (u16*)(ws + alloc(nQ * 2));
    u16* wvb = (u16*)(ws + alloc(nQ * 2));
    u16* wob = (u16*)(ws + alloc(nQ * 2));
    u16* w1b = (u16*)(ws + alloc(nF * 2));
    u16* w2b = (u16*)(ws + alloc(nF * 2));
    u16* w3b = (u16*)(ws + alloc(nF * 2));
    u16* woub = (u16*)(ws + alloc(nO * 2));

    CvtArgs ca;
    const float* srcs[8] = {wq, wk, wvw, wo, w1, w2, w3, w_out};
    u16* dsts[8] = {wqb, wkb, wvb, wob, w1b, w2b, w3b, woub};
    const size_t cnts[8] = {nQ, nQ, nQ, nQ, nF, nF, nF, nO};
    int cum = 0;
    for (int i = 0; i < 8; ++i) {
        ca.s[i] = srcs[i]; ca.d[i] = dsts[i]; ca.cum[i] = cum;
        cum += (int)(cnts[i] / 4);                 // granules of 4 elements (float4)
    }
    ca.cum[8] = cum;
    cvt_all_kernel<<<2048, 256, 0, stream>>>(ca);

    embed_kernel<<<SEQ, 256, 0, stream>>>(tokens, tok_emb, h);
    ropetab_kernel<<<(SEQ * 32) / 256, 256, 0, stream>>>(cosb, sinb);
    span_kernel<<<1, SEQ, 0, stream>>>(tokens, span, tmask);

    for (int l = 0; l < NLAY; ++l) {
        rmsnorm_kernel<<<SEQ, 256, 0, stream>>>(h, attn_nw + (size_t)l * DM, xn);
        qkv_kernel<<<dim3(8, 24), 256, 0, stream>>>(
            xn, wqb + (size_t)l * DM * DM, wkb + (size_t)l * DM * DM, wvb + (size_t)l * DM * DM,
            cosb, sinb, qb, kb, vb);
        fattn_kernel<<<dim3(SEQ / 64, NHEADS), 256, 0, stream>>>(qb, kb, vb, span, tmask, ab);
        gemm_p_kernel<1, 64, 64><<<dim3(16, 16), 256, 0, stream>>>(
            ab, wob + (size_t)l * DM * DM, h, h, DM, DM);

        rmsnorm_kernel<<<SEQ, 256, 0, stream>>>(h, ffn_nw + (size_t)l * DM, xn);
        ffn13_kernel<<<dim3(16, 22), 256, 0, stream>>>(
            xn, w1b + (size_t)l * FFD * DM, w3b + (size_t)l * FFD * DM, zb);
        gemm_p_kernel<1, 64, 64><<<dim3(16, 16), 256, 0, stream>>>(
            zb, w2b + (size_t)l * DM * FFD, h, h, DM, FFD);
    }

    rmsnorm_kernel<<<SEQ, 256, 0, stream>>>(h, final_nw, xn);
    gemm_big_kernel<0><<<dim3(SEQ / 256, VOC / 256), 512, 0, stream>>>(
        xn, woub, logits, nullptr, VOC, DM);
}

// Round 11
// 356.111 us; speedup vs baseline: 1.1097x; 1.1097x over previous
//
#include <hip/hip_runtime.h>
#include <hip/hip_bf16.h>
#include <stdint.h>

typedef unsigned short u16;
typedef __bf16 bf16x8 __attribute__((ext_vector_type(8)));
typedef u16 u16x8 __attribute__((ext_vector_type(8)));
typedef float f32x4 __attribute__((ext_vector_type(4)));

#define SEQ   1024
#define DM    1024
#define NHEADS 16
#define HDIM  64
#define VOC   32000
#define FFD   2816
#define NLAY  2

__device__ __forceinline__ u16 f2b(float f) {
    unsigned x = __builtin_bit_cast(unsigned, f);
    unsigned r = x + 0x7fffu + ((x >> 16) & 1u);
    return (u16)(r >> 16);
}
__device__ __forceinline__ float b2f(u16 u) {
    unsigned x = ((unsigned)u) << 16;
    return __builtin_bit_cast(float, x);
}
__device__ __forceinline__ float grpmax16(float v) {
    v = fmaxf(v, __shfl_xor(v, 1)); v = fmaxf(v, __shfl_xor(v, 2));
    v = fmaxf(v, __shfl_xor(v, 4)); v = fmaxf(v, __shfl_xor(v, 8));
    return v;
}
__device__ __forceinline__ float grpsum16(float v) {
    v += __shfl_xor(v, 1); v += __shfl_xor(v, 2);
    v += __shfl_xor(v, 4); v += __shfl_xor(v, 8);
    return v;
}

// async global->LDS, 16 bytes per lane. LDS dest must be wave-uniform base + lane*16.
__device__ __forceinline__ void gll16(const void* g, void* l) {
    __builtin_amdgcn_global_load_lds(
        (__attribute__((address_space(1))) void*)(uintptr_t)g,
        (__attribute__((address_space(3))) void*)(uint32_t)(uintptr_t)l,
        16, 0, 0);
}
template <int N> __device__ __forceinline__ void vwait() {
    if constexpr (N == 0)       asm volatile("s_waitcnt vmcnt(0)" ::: "memory");
    else if constexpr (N == 4)  asm volatile("s_waitcnt vmcnt(4)" ::: "memory");
    else if constexpr (N == 8)  asm volatile("s_waitcnt vmcnt(8)" ::: "memory");
    else if constexpr (N == 10) asm volatile("s_waitcnt vmcnt(10)" ::: "memory");
    else if constexpr (N == 16) asm volatile("s_waitcnt vmcnt(16)" ::: "memory");
}
// bijective XCD swizzle for any nwg (m204): per-XCD contiguous logical chunks.
__device__ __forceinline__ int xcd_swz(int bid, int nwg) {
    const int q = nwg >> 3, r = nwg & 7;
    const int xcd = bid & 7, j = bid >> 3;
    const int start = (xcd < r) ? xcd * (q + 1) : r * (q + 1) + (xcd - r) * q;
    return start + j;
}

// ---------------- fp32 -> bf16 weight conversion (7 segments; w_out handled in-GEMM) ----------------
struct CvtArgs { const float* s[8]; u16* d[8]; int cum[9]; };
__global__ __launch_bounds__(256) void cvt_all_kernel(CvtArgs a) {
    const int stride = gridDim.x * 256;
    const int total = a.cum[8];
    for (int u = blockIdx.x * 256 + threadIdx.x; u < total; u += stride) {
        int g = 0;
#pragma unroll
        for (int k = 1; k < 8; ++k) g += (u >= a.cum[k]) ? 1 : 0;
        const int local = u - a.cum[g];
        const float4* sp = (const float4*)a.s[g] + (size_t)local * 4;
        const float4 x0 = sp[0], x1 = sp[1], x2 = sp[2], x3 = sp[3];
        ushort4 p0, p1, p2, p3;
        p0.x = f2b(x0.x); p0.y = f2b(x0.y); p0.z = f2b(x0.z); p0.w = f2b(x0.w);
        p1.x = f2b(x1.x); p1.y = f2b(x1.y); p1.z = f2b(x1.z); p1.w = f2b(x1.w);
        p2.x = f2b(x2.x); p2.y = f2b(x2.y); p2.z = f2b(x2.z); p2.w = f2b(x2.w);
        p3.x = f2b(x3.x); p3.y = f2b(x3.y); p3.z = f2b(x3.z); p3.w = f2b(x3.w);
        ushort4* dp = (ushort4*)a.d[g] + (size_t)local * 4;
        dp[0] = p0; dp[1] = p1; dp[2] = p2; dp[3] = p3;
    }
}

// ---------------- embedding gather ----------------
__global__ __launch_bounds__(256) void embed_kernel(const int* __restrict__ tok,
    const float* __restrict__ emb, float* __restrict__ h) {
    const int l = blockIdx.x;
    const int t = tok[l];
    ((float4*)(h + (size_t)l * DM))[threadIdx.x] =
        ((const float4*)(emb + (size_t)t * DM))[threadIdx.x];
}

// ---------------- rope tables ----------------
__global__ __launch_bounds__(256) void ropetab_kernel(float* __restrict__ cosb,
                                                      float* __restrict__ sinb) {
    const int idx = blockIdx.x * 256 + threadIdx.x;   // < SEQ*32
    const int l = idx >> 5, j = idx & 31;
    const float inv = __expf(-((float)j * (1.0f / 32.0f)) * 13.122363377404328f); // ln(500000)
    const float ang = (float)l * inv;
    cosb[idx] = cosf(ang);
    sinb[idx] = sinf(ang);
}

// ---------------- transfusion span ids + per-64-token-tile span bitmask ----------------
__global__ void span_kernel(const int* __restrict__ tok, int* __restrict__ span,
                            int* __restrict__ tmask) {
    __shared__ int sb[SEQ], se[SEQ];
    __shared__ int tm[SEQ / 64];
    const int t = threadIdx.x;
    const int v = tok[t];
    const int bo = (v == 31998) ? 1 : 0;
    const int eo = (v == 31999) ? 1 : 0;
    sb[t] = bo; se[t] = eo;
    if (t < SEQ / 64) tm[t] = 0;
    __syncthreads();
    for (int o = 1; o < SEQ; o <<= 1) {
        int a = 0, b = 0;
        if (t >= o) { a = sb[t - o]; b = se[t - o]; }
        __syncthreads();
        sb[t] += a; se[t] += b;
        __syncthreads();
    }
    const int bc = sb[t];
    const int ec = se[t] - eo;           // exclusive eoi cumsum
    const int id = (bc > ec) ? bc : 0;
    span[t] = id;
    if (id > 0) atomicOr(&tm[t >> 6], 1 << ((id - 1) & 31));
    __syncthreads();
    if (t < SEQ / 64) tmask[t] = tm[t];
}

// ---------------- rmsnorm (fp32 in -> bf16 out) ----------------
__global__ __launch_bounds__(256) void rmsnorm_kernel(const float* __restrict__ x,
    const float* __restrict__ w, u16* __restrict__ o) {
    const int row = blockIdx.x;
    const float4 xv = ((const float4*)(x + (size_t)row * DM))[threadIdx.x];
    float ss = xv.x * xv.x + xv.y * xv.y + xv.z * xv.z + xv.w * xv.w;
    for (int off = 32; off; off >>= 1) ss += __shfl_xor(ss, off);
    __shared__ float red[4];
    const int lane = threadIdx.x & 63, wvi = threadIdx.x >> 6;
    if (lane == 0) red[wvi] = ss;
    __syncthreads();
    const float tot = red[0] + red[1] + red[2] + red[3];
    const float sc = rsqrtf(tot * (1.0f / (float)DM) + 1e-5f);
    const float4 wv4 = ((const float4*)w)[threadIdx.x];
    ushort4 ov;
    ov.x = f2b(xv.x * sc * wv4.x);
    ov.y = f2b(xv.y * sc * wv4.y);
    ov.z = f2b(xv.z * sc * wv4.z);
    ov.w = f2b(xv.w * sc * wv4.w);
    ((ushort4*)(o + (size_t)row * DM))[threadIdx.x] = ov;
}

// ======================= pipelined GEMM (BK=64, counted vmcnt) =======================
// ---------------- generic pipelined GEMM, fp32 out (+optional residual) ----------------
template <int RESID, int BM, int BN>
__global__ __launch_bounds__(256) void gemm_p_kernel(const u16* __restrict__ A,
    const u16* __restrict__ B, float* __restrict__ C, const float* __restrict__ res,
    int N, int K) {
    constexpr int AL = BM / 32, BL = BN / 32, LOADS = AL + BL;
    constexpr int MF = BM / 32, NF = BN / 32;
    __shared__ __align__(16) u16 sA[2][BM * 64];
    __shared__ __align__(16) u16 sB[2][BN * 64];
    const int nwg = gridDim.x * gridDim.y;
    const int lid = xcd_swz(blockIdx.y * gridDim.x + blockIdx.x, nwg);
    const int tm = (lid % gridDim.x) * BM, tn = (lid / gridDim.x) * BN;
    const int tid = threadIdx.x, lane = tid & 63, wid = tid >> 6;
    const int wm = wid >> 1, wn = wid & 1, fr = lane & 15, g = lane >> 4;

    const u16* ap[AL]; const u16* bp[BL];
#pragma unroll
    for (int j = 0; j < AL; ++j) {
        const int idx = j * 256 + tid, r = idx >> 3, gr = (idx & 7) ^ (r & 7);
        ap[j] = A + (size_t)(tm + r) * K + gr * 8;
    }
#pragma unroll
    for (int j = 0; j < BL; ++j) {
        const int idx = j * 256 + tid, r = idx >> 3, gr = (idx & 7) ^ (r & 7);
        bp[j] = B + (size_t)(tn + r) * K + gr * 8;
    }

    f32x4 acc[MF][NF] = {};
    const int NT = K >> 6;
#pragma unroll
    for (int j = 0; j < AL; ++j) gll16(ap[j], &sA[0][(j * 256 + tid) * 8]);
#pragma unroll
    for (int j = 0; j < BL; ++j) gll16(bp[j], &sB[0][(j * 256 + tid) * 8]);

    int p = 0;
    for (int t = 0; t < NT; ++t) {
        if (t + 1 < NT) {
#pragma unroll
            for (int j = 0; j < AL; ++j) gll16(ap[j] + (t + 1) * 64, &sA[p ^ 1][(j * 256 + tid) * 8]);
#pragma unroll
            for (int j = 0; j < BL; ++j) gll16(bp[j] + (t + 1) * 64, &sB[p ^ 1][(j * 256 + tid) * 8]);
            vwait<LOADS>();
        } else {
            vwait<0>();
        }
        __builtin_amdgcn_s_barrier();          // all waves' tile-t data resident
        __builtin_amdgcn_sched_barrier(0);
        bf16x8 af[MF][2], bfv[NF][2];
#pragma unroll
        for (int m = 0; m < MF; ++m)
#pragma unroll
            for (int ks = 0; ks < 2; ++ks) {
                const int row = wm * (BM / 2) + m * 16 + fr;
                const int gr = (ks * 4 + g) ^ (row & 7);
                af[m][ks] = *(const bf16x8*)&sA[p][row * 64 + gr * 8];
            }
#pragma unroll
        for (int n = 0; n < NF; ++n)
#pragma unroll
            for (int ks = 0; ks < 2; ++ks) {
                const int row = wn * (BN / 2) + n * 16 + fr;
                const int gr = (ks * 4 + g) ^ (row & 7);
                bfv[n][ks] = *(const bf16x8*)&sB[p][row * 64 + gr * 8];
            }
        __builtin_amdgcn_s_setprio(1);
#pragma unroll
        for (int m = 0; m < MF; ++m)
#pragma unroll
            for (int n = 0; n < NF; ++n)
#pragma unroll
                for (int ks = 0; ks < 2; ++ks)
                    acc[m][n] = __builtin_amdgcn_mfma_f32_16x16x32_bf16(af[m][ks], bfv[n][ks], acc[m][n], 0, 0, 0);
        __builtin_amdgcn_s_setprio(0);
        __builtin_amdgcn_s_barrier();          // reads of buf p closed before next writes
        p ^= 1;
    }

    const int cr = (lane >> 4) * 4, cc = lane & 15;
#pragma unroll
    for (int m = 0; m < MF; ++m)
#pragma unroll
        for (int n = 0; n < NF; ++n) {
            const int row0 = tm + wm * (BM / 2) + m * 16 + cr;
            const int col = tn + wn * (BN / 2) + n * 16 + cc;
#pragma unroll
            for (int r = 0; r < 4; ++r) {
                const size_t idx = (size_t)(row0 + r) * N + col;
                float v = acc[m][n][r];
                if (RESID) v += res[idx];
                C[idx] = v;
            }
        }
}

// ======================= 256x256 / BK=64 / 8-wave phase-interleaved GEMM, fp32 B =======================
// A (bf16) staged via gll16 (pre-swizzled source). B (fp32) reg-staged: coalesced float4
// loads -> (__bf16) cvt -> swizzled ds_write_b128 (both-sides swizzle, read XOR unchanged).
// B staging split in 2 half-rounds interleaved with the 4 MFMA phases; tile-end
// __syncthreads drains everything (A gll16 included).
template <int RESID>
__global__ __launch_bounds__(512, 2) void gemm_big_kernel(const u16* __restrict__ A,
    const float* __restrict__ B, float* __restrict__ C, const float* __restrict__ res,
    int N, int K) {
    __shared__ __align__(16) u16 sA[2][256 * 64];
    __shared__ __align__(16) u16 sB[2][256 * 64];
    const int nwg = gridDim.x * gridDim.y;
    const int lid = xcd_swz(blockIdx.y * gridDim.x + blockIdx.x, nwg);
    const int tm = (lid % gridDim.x) * 256;
    const int tn = (lid / gridDim.x) * 256;
    const int tid = threadIdx.x, lane = tid & 63, wid = tid >> 6;
    const int wm = wid >> 2, wn = wid & 3;       // 2 x 4 waves, per-wave 128x64
    const int fr = lane & 15, g = lane >> 4;

    // A: pre-swizzled global source, linear LDS dest.
    const u16* ap[4];
#pragma unroll
    for (int j = 0; j < 4; ++j) {
        const int idx = j * 512 + tid, r = idx >> 3, gr = (idx & 7) ^ (r & 7);
        ap[j] = A + (size_t)(tm + r) * K + gr * 8;
    }
    // B: thread owns granules G = j*512+tid (granule = 8 fp32 -> 8 bf16 = one b128).
    const float* bp[4];
    int bst[4];
#pragma unroll
    for (int j = 0; j < 4; ++j) {
        const int G = j * 512 + tid, r = G >> 3, gr = G & 7;
        bp[j] = B + (size_t)(tn + r) * K + gr * 8;
        bst[j] = r * 64 + ((gr ^ (r & 7)) * 8);     // swizzled LDS element offset
    }

    auto cvtst = [&](int b, int j, const float4& x0, const float4& x1) {
        bf16x8 v;
        v[0] = (__bf16)x0.x; v[1] = (__bf16)x0.y; v[2] = (__bf16)x0.z; v[3] = (__bf16)x0.w;
        v[4] = (__bf16)x1.x; v[5] = (__bf16)x1.y; v[6] = (__bf16)x1.z; v[7] = (__bf16)x1.w;
        *(bf16x8*)&sB[b][bst[j]] = v;
    };

    f32x4 acc[8][4] = {};
    const int NT = K >> 6;

    {   // prologue: stage tile 0 into buf 0
#pragma unroll
        for (int j = 0; j < 4; ++j) gll16(ap[j], &sA[0][(j * 512 + tid) * 8]);
        float4 b0 = *(const float4*)(bp[0]), b1 = *(const float4*)(bp[0] + 4);
        float4 b2 = *(const float4*)(bp[1]), b3 = *(const float4*)(bp[1] + 4);
        cvtst(0, 0, b0, b1); cvtst(0, 1, b2, b3);
        b0 = *(const float4*)(bp[2]); b1 = *(const float4*)(bp[2] + 4);
        b2 = *(const float4*)(bp[3]); b3 = *(const float4*)(bp[3] + 4);
        cvtst(0, 2, b0, b1); cvtst(0, 3, b2, b3);
        __syncthreads();
    }

    int p = 0;
    for (int t = 0; t < NT; ++t) {
        const bool pre = (t + 1 < NT);
        float4 b0, b1, b2, b3;
        if (pre) {
#pragma unroll
            for (int j = 0; j < 4; ++j) gll16(ap[j] + (t + 1) * 64, &sA[p ^ 1][(j * 512 + tid) * 8]);
            b0 = *(const float4*)(bp[0] + (t + 1) * 64); b1 = *(const float4*)(bp[0] + (t + 1) * 64 + 4);
            b2 = *(const float4*)(bp[1] + (t + 1) * 64); b3 = *(const float4*)(bp[1] + (t + 1) * 64 + 4);
        }
        bf16x8 bfv[4][2];
#pragma unroll
        for (int mq = 0; mq < 4; ++mq) {         // 4 phases per K-tile
            if (mq == 0) {
#pragma unroll
                for (int n = 0; n < 4; ++n)
#pragma unroll
                    for (int ks = 0; ks < 2; ++ks) {
                        const int row = wn * 64 + n * 16 + fr;
                        const int gr = (ks * 4 + g) ^ (row & 7);
                        bfv[n][ks] = *(const bf16x8*)&sB[p][row * 64 + gr * 8];
                    }
            }
            if (mq == 2 && pre) {                // mid-tile: commit first half, load second
                cvtst(p ^ 1, 0, b0, b1); cvtst(p ^ 1, 1, b2, b3);
                b0 = *(const float4*)(bp[2] + (t + 1) * 64); b1 = *(const float4*)(bp[2] + (t + 1) * 64 + 4);
                b2 = *(const float4*)(bp[3] + (t + 1) * 64); b3 = *(const float4*)(bp[3] + (t + 1) * 64 + 4);
            }
            bf16x8 af[2][2];
#pragma unroll
            for (int i = 0; i < 2; ++i)
#pragma unroll
                for (int ks = 0; ks < 2; ++ks) {
                    const int row = wm * 128 + (mq * 2 + i) * 16 + fr;
                    const int gr = (ks * 4 + g) ^ (row & 7);
                    af[i][ks] = *(const bf16x8*)&sA[p][row * 64 + gr * 8];
                }
            __builtin_amdgcn_s_setprio(1);
#pragma unroll
            for (int i = 0; i < 2; ++i)
#pragma unroll
                for (int n = 0; n < 4; ++n)
#pragma unroll
                    for (int ks = 0; ks < 2; ++ks)
                        acc[mq * 2 + i][n] = __builtin_amdgcn_mfma_f32_16x16x32_bf16(
                            af[i][ks], bfv[n][ks], acc[mq * 2 + i][n], 0, 0, 0);
            __builtin_amdgcn_s_setprio(0);
            if (mq < 3) __builtin_amdgcn_s_barrier();   // phase boundary
        }
        if (pre) { cvtst(p ^ 1, 2, b0, b1); cvtst(p ^ 1, 3, b2, b3); }
        __syncthreads();     // drain vm+lgkm; publish buf p^1; close reads of p
        p ^= 1;
    }

    const int cr = (lane >> 4) * 4, cc = lane & 15;
#pragma unroll
    for (int m = 0; m < 8; ++m)
#pragma unroll
        for (int n = 0; n < 4; ++n) {
            const int row0 = tm + wm * 128 + m * 16 + cr;
            const int col = tn + wn * 64 + n * 16 + cc;
#pragma unroll
            for (int r = 0; r < 4; ++r) {
                const size_t idx = (size_t)(row0 + r) * N + col;
                float v = acc[m][n][r];
                if (RESID) v += res[idx];
                C[idx] = v;
            }
        }
}

// ---------------- fused QKV GEMM (128x128) + RoPE + bf16 cast ----------------
__global__ __launch_bounds__(256) void qkv_kernel(const u16* __restrict__ A,
    const u16* __restrict__ Bq, const u16* __restrict__ Bk, const u16* __restrict__ Bv,
    const float* __restrict__ cosb, const float* __restrict__ sinb,
    u16* __restrict__ qb, u16* __restrict__ kb, u16* __restrict__ vb) {
    __shared__ __align__(16) u16 sA[2][128 * 64];
    __shared__ __align__(16) u16 sB[2][128 * 64];
    const int lid = xcd_swz(blockIdx.y * gridDim.x + blockIdx.x, 8 * 24);
    const int tm = (lid % 8) * 128;
    const int yy = lid / 8;
    const int mat = yy >> 3;
    const int tn = (yy & 7) * 128;
    const u16* B = (mat == 0) ? Bq : (mat == 1) ? Bk : Bv;
    u16* out = (mat == 0) ? qb : (mat == 1) ? kb : vb;
    const int tid = threadIdx.x, lane = tid & 63, wid = tid >> 6;
    const int wm = wid >> 1, wn = wid & 1, fr = lane & 15, g = lane >> 4;

    const u16* ap[4]; const u16* bp[4];
#pragma unroll
    for (int j = 0; j < 4; ++j) {
        const int idx = j * 256 + tid, r = idx >> 3, gr = (idx & 7) ^ (r & 7);
        ap[j] = A + (size_t)(tm + r) * DM + gr * 8;
        bp[j] = B + (size_t)(tn + r) * DM + gr * 8;
    }

    f32x4 acc[4][4] = {};
#pragma unroll
    for (int j = 0; j < 4; ++j) gll16(ap[j], &sA[0][(j * 256 + tid) * 8]);
#pragma unroll
    for (int j = 0; j < 4; ++j) gll16(bp[j], &sB[0][(j * 256 + tid) * 8]);

    int p = 0;
    for (int t = 0; t < DM / 64; ++t) {
        if (t + 1 < DM / 64) {
#pragma unroll
            for (int j = 0; j < 4; ++j) gll16(ap[j] + (t + 1) * 64, &sA[p ^ 1][(j * 256 + tid) * 8]);
#pragma unroll
            for (int j = 0; j < 4; ++j) gll16(bp[j] + (t + 1) * 64, &sB[p ^ 1][(j * 256 + tid) * 8]);
            vwait<8>();
        } else {
            vwait<0>();
        }
        __builtin_amdgcn_s_barrier();
        __builtin_amdgcn_sched_barrier(0);
        bf16x8 af[4][2], bfv[4][2];
#pragma unroll
        for (int m = 0; m < 4; ++m)
#pragma unroll
            for (int ks = 0; ks < 2; ++ks) {
                const int row = wm * 64 + m * 16 + fr;
                const int gr = (ks * 4 + g) ^ (row & 7);
                af[m][ks] = *(const bf16x8*)&sA[p][row * 64 + gr * 8];
            }
#pragma unroll
        for (int n = 0; n < 4; ++n)
#pragma unroll
            for (int ks = 0; ks < 2; ++ks) {
                const int row = wn * 64 + n * 16 + fr;
                const int gr = (ks * 4 + g) ^ (row & 7);
                bfv[n][ks] = *(const bf16x8*)&sB[p][row * 64 + gr * 8];
            }
        __builtin_amdgcn_s_setprio(1);
#pragma unroll
        for (int m = 0; m < 4; ++m)
#pragma unroll
            for (int n = 0; n < 4; ++n)
#pragma unroll
                for (int ks = 0; ks < 2; ++ks)
                    acc[m][n] = __builtin_amdgcn_mfma_f32_16x16x32_bf16(af[m][ks], bfv[n][ks], acc[m][n], 0, 0, 0);
        __builtin_amdgcn_s_setprio(0);
        __builtin_amdgcn_s_barrier();
        p ^= 1;
    }

    const int cr = (lane >> 4) * 4, cc = lane & 15;
    if (mat < 2) {
#pragma unroll
        for (int m = 0; m < 4; ++m)
#pragma unroll
            for (int n = 0; n < 4; ++n) {
                const int row0 = tm + wm * 64 + m * 16 + cr;
                const int col = tn + wn * 64 + n * 16 + cc;
                const int j = (n * 16 + cc) >> 1;    // rope pair index within head
#pragma unroll
                for (int r = 0; r < 4; ++r) {
                    const int row = row0 + r;
                    const float c = cosb[row * 32 + j];
                    const float s = sinb[row * 32 + j];
                    const float v = acc[m][n][r];
                    const float pv = __shfl_xor(v, 1);
                    const float o = (cc & 1) ? (pv * s + v * c) : (v * c - pv * s);
                    out[(size_t)row * DM + col] = f2b(o);
                }
            }
    } else {
#pragma unroll
        for (int m = 0; m < 4; ++m)
#pragma unroll
            for (int n = 0; n < 4; ++n) {
                const int row0 = tm + wm * 64 + m * 16 + cr;
                const int col = tn + wn * 64 + n * 16 + cc;
#pragma unroll
                for (int r = 0; r < 4; ++r)
                    out[(size_t)(row0 + r) * DM + col] = f2b(acc[m][n][r]);
            }
    }
}

// ---------------- fused w1/w3 GEMM (64x128 dual-B) + SiLU*mul -> bf16 ----------------
__global__ __launch_bounds__(256) void ffn13_kernel(const u16* __restrict__ A,
    const u16* __restrict__ B1, const u16* __restrict__ B3, u16* __restrict__ Z) {
    __shared__ __align__(16) u16 sA[2][64 * 64];
    __shared__ __align__(16) u16 sB1[2][128 * 64];
    __shared__ __align__(16) u16 sB3[2][128 * 64];
    const int lid = xcd_swz(blockIdx.y * gridDim.x + blockIdx.x, 16 * 22);
    const int tm = (lid % 16) * 64;
    const int tn = (lid / 16) * 128;
    const int tid = threadIdx.x, lane = tid & 63, wid = tid >> 6;
    const int wm = wid >> 1, wn = wid & 1, fr = lane & 15, g = lane >> 4;

    const u16* ap[2]; const u16* b1p[4]; const u16* b3p[4];
#pragma unroll
    for (int j = 0; j < 2; ++j) {
        const int idx = j * 256 + tid, r = idx >> 3, gr = (idx & 7) ^ (r & 7);
        ap[j] = A + (size_t)(tm + r) * DM + gr * 8;
    }
#pragma unroll
    for (int j = 0; j < 4; ++j) {
        const int idx = j * 256 + tid, r = idx >> 3, gr = (idx & 7) ^ (r & 7);
        b1p[j] = B1 + (size_t)(tn + r) * DM + gr * 8;
        b3p[j] = B3 + (size_t)(tn + r) * DM + gr * 8;
    }

    f32x4 acc1[2][4] = {}, acc3[2][4] = {};
#pragma unroll
    for (int j = 0; j < 2; ++j) gll16(ap[j], &sA[0][(j * 256 + tid) * 8]);
#pragma unroll
    for (int j = 0; j < 4; ++j) gll16(b1p[j], &sB1[0][(j * 256 + tid) * 8]);
#pragma unroll
    for (int j = 0; j < 4; ++j) gll16(b3p[j], &sB3[0][(j * 256 + tid) * 8]);

    int p = 0;
    for (int t = 0; t < DM / 64; ++t) {
        if (t + 1 < DM / 64) {
#pragma unroll
            for (int j = 0; j < 2; ++j) gll16(ap[j] + (t + 1) * 64, &sA[p ^ 1][(j * 256 + tid) * 8]);
#pragma unroll
            for (int j = 0; j < 4; ++j) gll16(b1p[j] + (t + 1) * 64, &sB1[p ^ 1][(j * 256 + tid) * 8]);
#pragma unroll
            for (int j = 0; j < 4; ++j) gll16(b3p[j] + (t + 1) * 64, &sB3[p ^ 1][(j * 256 + tid) * 8]);
            vwait<10>();
        } else {
            vwait<0>();
        }
        __builtin_amdgcn_s_barrier();
        __builtin_amdgcn_sched_barrier(0);
        bf16x8 af[2][2], b1v[4][2], b3v[4][2];
#pragma unroll
        for (int m = 0; m < 2; ++m)
#pragma unroll
            for (int ks = 0; ks < 2; ++ks) {
                const int row = wm * 32 + m * 16 + fr;
                const int gr = (ks * 4 + g) ^ (row & 7);
                af[m][ks] = *(const bf16x8*)&sA[p][row * 64 + gr * 8];
            }
#pragma unroll
        for (int n = 0; n < 4; ++n)
#pragma unroll
            for (int ks = 0; ks < 2; ++ks) {
                const int row = wn * 64 + n * 16 + fr;
                const int gr = (ks * 4 + g) ^ (row & 7);
                b1v[n][ks] = *(const bf16x8*)&sB1[p][row * 64 + gr * 8];
                b3v[n][ks] = *(const bf16x8*)&sB3[p][row * 64 + gr * 8];
            }
        __builtin_amdgcn_s_setprio(1);
#pragma unroll
        for (int m = 0; m < 2; ++m)
#pragma unroll
            for (int n = 0; n < 4; ++n)
#pragma unroll
                for (int ks = 0; ks < 2; ++ks) {
                    acc1[m][n] = __builtin_amdgcn_mfma_f32_16x16x32_bf16(af[m][ks], b1v[n][ks], acc1[m][n], 0, 0, 0);
                    acc3[m][n] = __builtin_amdgcn_mfma_f32_16x16x32_bf16(af[m][ks], b3v[n][ks], acc3[m][n], 0, 0, 0);
                }
        __builtin_amdgcn_s_setprio(0);
        __builtin_amdgcn_s_barrier();
        p ^= 1;
    }

    const int cr = (lane >> 4) * 4, cc = lane & 15;
#pragma unroll
    for (int m = 0; m < 2; ++m)
#pragma unroll
        for (int n = 0; n < 4; ++n) {
            const int row0 = tm + wm * 32 + m * 16 + cr;
            const int col = tn + wn * 64 + n * 16 + cc;
#pragma unroll
            for (int r = 0; r < 4; ++r) {
                const float a1 = acc1[m][n][r];
                const float a3 = acc3[m][n][r];
                const float z = a1 / (1.f + __expf(-a1)) * a3;
                Z[(size_t)(row0 + r) * FFD + col] = f2b(z);
            }
        }
}

// ---------------- flash attention: block = (64 q-rows, 1 head), 4 waves ----------------
__global__ __launch_bounds__(256) void fattn_kernel(const u16* __restrict__ qb,
    const u16* __restrict__ kb, const u16* __restrict__ vb,
    const int* __restrict__ span, const int* __restrict__ tmask, u16* __restrict__ ob) {
    __shared__ __align__(16) u16 sK[64][72];   // K rows, padded
    __shared__ __align__(16) u16 sVT[64][72];  // V transposed: [d][key]
    __shared__ __align__(16) u16 sP[4][16][72];// per-wave P tile
    const int tid = threadIdx.x, lane = tid & 63, wq = tid >> 6;
    const int g = lane >> 4, fr = lane & 15;
    const int head = blockIdx.y;
    const int qbase = blockIdx.x * 64;
    const int qmask = tmask[blockIdx.x];

    bf16x8 qfr[2];
    {
        const u16* qp = qb + (size_t)(qbase + wq * 16 + fr) * DM + head * HDIM + g * 8;
        qfr[0] = *(const bf16x8*)(qp);
        qfr[1] = *(const bf16x8*)(qp + 32);
    }
    int sq[4];
#pragma unroll
    for (int r = 0; r < 4; ++r) sq[r] = span[qbase + wq * 16 + g * 4 + r];

    float m_old[4] = {-1e30f, -1e30f, -1e30f, -1e30f};
    float lsum[4] = {0.f, 0.f, 0.f, 0.f};
    f32x4 acc[4] = {};

    for (int kt = 0; kt < SEQ / 64; ++kt) {
        const int kb0 = kt * 64;
        if (kb0 > qbase && (qmask & tmask[kt]) == 0) continue;   // block-uniform skip
        __syncthreads();
        {
            const int r = tid >> 2, c0 = (tid & 3) * 16;
            const u16* src = kb + (size_t)(kb0 + r) * DM + head * HDIM + c0;
            *(u16x8*)&sK[r][c0]     = *(const u16x8*)(src);
            *(u16x8*)&sK[r][c0 + 8] = *(const u16x8*)(src + 8);
        }
        {
            const int k = tid & 63, d0 = (tid >> 6) * 16;
            const u16* src = vb + (size_t)(kb0 + k) * DM + head * HDIM + d0;
            const u16x8 v0 = *(const u16x8*)(src);
            const u16x8 v1 = *(const u16x8*)(src + 8);
#pragma unroll
            for (int j = 0; j < 8; ++j) {
                sVT[d0 + j][k]     = v0[j];
                sVT[d0 + 8 + j][k] = v1[j];
            }
        }
        __syncthreads();

        f32x4 accs[4] = {};
        __builtin_amdgcn_s_setprio(1);
#pragma unroll
        for (int nf = 0; nf < 4; ++nf)
#pragma unroll
            for (int kf = 0; kf < 2; ++kf) {
                const bf16x8 kfv = *(const bf16x8*)&sK[nf * 16 + fr][g * 8 + kf * 32];
                accs[nf] = __builtin_amdgcn_mfma_f32_16x16x32_bf16(qfr[kf], kfv, accs[nf], 0, 0, 0);
            }
        __builtin_amdgcn_s_setprio(0);

        float sv[4][4]; bool al[4][4];
        if (kb0 + 63 <= qbase) {             // fully-causal tile: all allowed
#pragma unroll
            for (int nf = 0; nf < 4; ++nf)
#pragma unroll
                for (int r = 0; r < 4; ++r) {
                    al[nf][r] = true;
                    sv[nf][r] = accs[nf][r] * 0.125f;
                }
        } else {
            int spk[4];
#pragma unroll
            for (int nf = 0; nf < 4; ++nf) spk[nf] = span[kb0 + nf * 16 + fr];
#pragma unroll
            for (int nf = 0; nf < 4; ++nf) {
                const int key = kb0 + nf * 16 + fr;
#pragma unroll
                for (int r = 0; r < 4; ++r) {
                    const int q = qbase + wq * 16 + g * 4 + r;
                    al[nf][r] = (key <= q) || (sq[r] > 0 && spk[nf] == sq[r]);
                    sv[nf][r] = al[nf][r] ? accs[nf][r] * 0.125f : -1e30f;
                }
            }
        }
        float alpha[4], ls[4];
#pragma unroll
        for (int r = 0; r < 4; ++r) {
            float mn = fmaxf(fmaxf(sv[0][r], sv[1][r]), fmaxf(sv[2][r], sv[3][r]));
            mn = grpmax16(mn);
            const float mnew = fmaxf(m_old[r], mn);
            alpha[r] = __expf(m_old[r] - mnew);
            m_old[r] = mnew;
            ls[r] = 0.f;
        }
        u16 pb[4][4];
#pragma unroll
        for (int nf = 0; nf < 4; ++nf)
#pragma unroll
            for (int r = 0; r < 4; ++r) {
                const float p = al[nf][r] ? __expf(sv[nf][r] - m_old[r]) : 0.f;
                ls[r] += p;
                pb[nf][r] = f2b(p);
            }
#pragma unroll
        for (int r = 0; r < 4; ++r) {
            lsum[r] = lsum[r] * alpha[r] + grpsum16(ls[r]);
#pragma unroll
            for (int nf = 0; nf < 4; ++nf) acc[nf][r] *= alpha[r];
        }
#pragma unroll
        for (int nf = 0; nf < 4; ++nf)
#pragma unroll
            for (int r = 0; r < 4; ++r)
                sP[wq][g * 4 + r][nf * 16 + fr] = pb[nf][r];

        __builtin_amdgcn_s_setprio(1);
#pragma unroll
        for (int nf = 0; nf < 4; ++nf)
#pragma unroll
            for (int kf = 0; kf < 2; ++kf) {
                const bf16x8 pa  = *(const bf16x8*)&sP[wq][fr][g * 8 + kf * 32];
                const bf16x8 vtb = *(const bf16x8*)&sVT[nf * 16 + fr][g * 8 + kf * 32];
                acc[nf] = __builtin_amdgcn_mfma_f32_16x16x32_bf16(pa, vtb, acc[nf], 0, 0, 0);
            }
        __builtin_amdgcn_s_setprio(0);
    }

#pragma unroll
    for (int nf = 0; nf < 4; ++nf)
#pragma unroll
        for (int r = 0; r < 4; ++r) {
            const int q = qbase + wq * 16 + g * 4 + r;
            const int d = nf * 16 + fr;
            ob[(size_t)q * DM + head * HDIM + d] = f2b(acc[nf][r] / lsum[r]);
        }
}

extern "C" void kernel_launch(void* const* d_in, const int* in_sizes, int n_in,
                              void* d_out, int out_size, void* d_ws, size_t ws_size,
                              hipStream_t stream) {
    (void)in_sizes; (void)n_in; (void)out_size; (void)ws_size;
    const int*   tokens   = (const int*)d_in[0];
    const float* tok_emb  = (const float*)d_in[1];
    const float* wq       = (const float*)d_in[2];
    const float* wk       = (const float*)d_in[3];
    const float* wvw      = (const float*)d_in[4];
    const float* wo       = (const float*)d_in[5];
    const float* w1       = (const float*)d_in[6];
    const float* w2       = (const float*)d_in[7];
    const float* w3       = (const float*)d_in[8];
    const float* attn_nw  = (const float*)d_in[9];
    const float* ffn_nw   = (const float*)d_in[10];
    const float* final_nw = (const float*)d_in[11];
    const float* w_out    = (const float*)d_in[12];
    float* logits = (float*)d_out;

    char* ws = (char*)d_ws;
    size_t off = 0;
    auto alloc = [&](size_t b) { size_t o = off; off += (b + 255) & ~(size_t)255; return o; };
    float* h    = (float*)(ws + alloc((size_t)SEQ * DM * 4));
    u16*   xn   = (u16*)  (ws + alloc((size_t)SEQ * DM * 2));
    u16*   qb   = (u16*)  (ws + alloc((size_t)SEQ * DM * 2));
    u16*   kb   = (u16*)  (ws + alloc((size_t)SEQ * DM * 2));
    u16*   vb   = (u16*)  (ws + alloc((size_t)SEQ * DM * 2));
    u16*   ab   = (u16*)  (ws + alloc((size_t)SEQ * DM * 2));
    u16*   zb   = (u16*)  (ws + alloc((size_t)SEQ * FFD * 2));
    float* cosb = (float*)(ws + alloc((size_t)SEQ * 32 * 4));
    float* sinb = (float*)(ws + alloc((size_t)SEQ * 32 * 4));
    int*   span = (int*)  (ws + alloc((size_t)SEQ * 4));
    int*   tmask= (int*)  (ws + alloc((size_t)(SEQ / 64) * 4));
    // bf16 weight copies (w_out stays fp32, consumed directly by gemm_big)
    const size_t nQ = (size_t)NLAY * DM * DM;     // wq/wk/wv/wo each
    const size_t nF = (size_t)NLAY * FFD * DM;    // w1/w2/w3 each
    u16* wqb = (u16*)(ws + alloc(nQ * 2));
    u16* wkb = (u16*)(ws + alloc(nQ * 2));
    u16* wvb = (u16*)(ws + alloc(nQ * 2));
    u16* wob = (u16*)(ws + alloc(nQ * 2));
    u16* w1b = (u16*)(ws + alloc(nF * 2));
    u16* w2b = (u16*)(ws + alloc(nF * 2));
    u16* w3b = (u16*)(ws + alloc(nF * 2));

    CvtArgs ca;
    const float* srcs[7] = {wq, wk, wvw, wo, w1, w2, w3};
    u16* dsts[7] = {wqb, wkb, wvb, wob, w1b, w2b, w3b};
    const size_t cnts[7] = {nQ, nQ, nQ, nQ, nF, nF, nF};
    int cum = 0;
    for (int i = 0; i < 7; ++i) {
        ca.s[i] = srcs[i]; ca.d[i] = dsts[i]; ca.cum[i] = cum;
        cum += (int)(cnts[i] / 16);                // granules of 16 elements
    }
    ca.s[7] = wq; ca.d[7] = wqb;                   // unused (empty segment)
    ca.cum[7] = cum; ca.cum[8] = cum;
    cvt_all_kernel<<<2048, 256, 0, stream>>>(ca);

    embed_kernel<<<SEQ, 256, 0, stream>>>(tokens, tok_emb, h);
    ropetab_kernel<<<(SEQ * 32) / 256, 256, 0, stream>>>(cosb, sinb);
    span_kernel<<<1, SEQ, 0, stream>>>(tokens, span, tmask);

    for (int l = 0; l < NLAY; ++l) {
        rmsnorm_kernel<<<SEQ, 256, 0, stream>>>(h, attn_nw + (size_t)l * DM, xn);
        qkv_kernel<<<dim3(8, 24), 256, 0, stream>>>(
            xn, wqb + (size_t)l * DM * DM, wkb + (size_t)l * DM * DM, wvb + (size_t)l * DM * DM,
            cosb, sinb, qb, kb, vb);
        fattn_kernel<<<dim3(SEQ / 64, NHEADS), 256, 0, stream>>>(qb, kb, vb, span, tmask, ab);
        gemm_p_kernel<1, 64, 64><<<dim3(16, 16), 256, 0, stream>>>(
            ab, wob + (size_t)l * DM * DM, h, h, DM, DM);

        rmsnorm_kernel<<<SEQ, 256, 0, stream>>>(h, ffn_nw + (size_t)l * DM, xn);
        ffn13_kernel<<<dim3(16, 22), 256, 0, stream>>>(
            xn, w1b + (size_t)l * FFD * DM, w3b + (size_t)l * FFD * DM, zb);
        gemm_p_kernel<1, 64, 64><<<dim3(16, 16), 256, 0, stream>>>(
            zb, w2b + (size_t)l * DM * FFD, h, h, DM, FFD);
    }

    rmsnorm_kernel<<<SEQ, 256, 0, stream>>>(h, final_nw, xn);
    gemm_big_kernel<0><<<dim3(SEQ / 256, VOC / 256), 512, 0, stream>>>(
        xn, w_out, logits, nullptr, VOC, DM);
}